// Round 16
// baseline (413.739 us; speedup 1.0000x reference)
//
#include <hip/hip_runtime.h>
#include <cfloat>

// Problem constants (match reference)
constexpr int Bn = 1024, Ln = 1024, Vn = 20, Dn = 128;
constexpr int NJ = 2 * Vn;      // 40 output columns
constexpr int TB = 32;          // steps per block (resync every 2 blocks)

// v mod 20 for 0 <= v <= ~4000 (magic multiply, exact in this range)
__device__ __forceinline__ int mod20(int v) { return v - 20 * ((v * 205) >> 12); }

// ---- DPP helpers (16-lane row reduce, pure VALU) ----
template<int CTRL>
__device__ __forceinline__ float dpp_mov(float v) {
  return __int_as_float(
      __builtin_amdgcn_update_dpp(0, __float_as_int(v), CTRL, 0xF, 0xF, false));
}
template<int CTRL>
__device__ __forceinline__ float dpp_max(float v) {
  return fmaxf(v, dpp_mov<CTRL>(v));
}
__device__ __forceinline__ float max3f(float a, float b, float c) {
  return fmaxf(fmaxf(a, b), c);   // fuses to v_max3_f32
}
// 3-level reduce (proven R13): pair max, then max3 over rotations.
__device__ __forceinline__ float rowmax16(float v) {
  const float a1 = dpp_max<0xB1>(v);                               // pair max
  const float t2 = max3f(a1, dpp_mov<0x122>(a1), dpp_mov<0x124>(a1));
  return max3f(t2, dpp_mov<0x126>(t2), dpp_mov<0x12C>(t2));
}

// inv mod 20 packed table: 5-bit entries for odd s, indexed by s>>1
constexpr unsigned long long INVT =
    (1ull << 0) | (7ull << 5) | (0ull << 10) | (3ull << 15) | (9ull << 20) |
    (11ull << 25) | (17ull << 30) | (0ull << 35) | (13ull << 40) | (19ull << 45);

// EW column into named, PINNED VGPRs (R10-proven pattern: pins hold).
#define ELOAD(k) float eL##k, eH##k; \
  { const float2 _e = ew2[(k) * 32 + pos]; eL##k = _e.x; eH##k = _e.y; } \
  asm volatile("" : "+v"(eL##k), "+v"(eH##k));

__global__ __launch_bounds__(64, 1) void daf_chain(
    const float* __restrict__ x, const float* __restrict__ emb,
    const float* __restrict__ W, const float* __restrict__ bvec,
    float* __restrict__ out)
{
  __shared__ float Ws[Dn * NJ];                  // 20480 B: W row-major f32
  __shared__ float embd[Vn * Dn];                // 10240 B: emb rows f32
  __shared__ alignas(8) float ewd2[Vn * 64];     //  5120 B: EW distributed {lo,hi}/pos
  __shared__ alignas(16) double st64[Dn];        //  1024 B: f64 copy of f32 state
  __shared__ float nets40[64];                   //   256 B: resync share (padded)
  __shared__ alignas(16) unsigned char aidx[Ln]; //  1024 B: token index per step

  const int lane = threadIdx.x;
  const int batch = blockIdx.x;
  const int p   = lane & 15;          // position within row
  const int rB  = (lane >> 4) & 1;    // 0 = loc row, 1 = scale row
  const int pos = lane & 31;          // row-pair position (lanes 32..63 mirror)

  // resync column ownership (40 owner lanes)
  const bool own = (lane < Vn) || (lane >= 32 && lane < 32 + Vn);
  const int  jm  = (lane < 32) ? lane : (lane - 32 + Vn);
  const int  jc  = own ? jm : 0;

  // ---- Prologue: stage W, emb; extract token indices (coalesced float4) ----
  // Single-wave block: LDS ops complete in-order within the wave -> no barriers.
  for (int i = lane; i < Dn * NJ; i += 64) Ws[i] = W[i];
  for (int i = lane; i < Vn * Dn; i += 64) embd[i] = emb[i];
  const float4* xb4 = (const float4*)(x + (size_t)batch * Ln * Vn);
  for (int i = lane; i < Ln * (Vn / 4); i += 64) {
    const float4 v = xb4[i];
    const int row = i / 5, cb = (i % 5) * 4;
    if (v.x > 0.5f) aidx[row] = (unsigned char)(cb + 0);
    if (v.y > 0.5f) aidx[row] = (unsigned char)(cb + 1);
    if (v.z > 0.5f) aidx[row] = (unsigned char)(cb + 2);
    if (v.w > 0.5f) aidx[row] = (unsigned char)(cb + 3);
  }

  // ---- EW[k][j] = f64 dot(emb[k], W[:,j]) -> f32, distributed layout (R7) ----
  for (int e = lane; e < Vn * NJ; e += 64) {
    const int k = e / NJ, j = e - k * NJ;
    double acc = 0.0;
#pragma unroll 4
    for (int d = 0; d < Dn; ++d)
      acc = __builtin_fma((double)embd[k * Dn + d], (double)Ws[d * NJ + j], acc);
    int q, slot;
    if (j < 16)      { q = j;             slot = 0; }
    else if (j < 20) { q = j - 16;        slot = 1; }
    else if (j < 36) { q = 16 + (j - 20); slot = 0; }
    else             { q = 16 + (j - 36); slot = 1; }
    ewd2[k * 64 + q * 2 + slot] = (float)acc;
  }
  if ((pos & 15) >= 4)   // zero undefined hi slots so (-FLT_MAX += 0) stays put
    for (int k = 0; k < Vn; ++k) ewd2[k * 64 + pos * 2 + 1] = 0.0f;

  // ---- EW column into 40 named pinned VGPRs (same f32 values as ds_read path) ----
  const float2* ew2 = (const float2*)ewd2;
  ELOAD(0)  ELOAD(1)  ELOAD(2)  ELOAD(3)  ELOAD(4)
  ELOAD(5)  ELOAD(6)  ELOAD(7)  ELOAD(8)  ELOAD(9)
  ELOAD(10) ELOAD(11) ELOAD(12) ELOAD(13) ELOAD(14)
  ELOAD(15) ELOAD(16) ELOAD(17) ELOAD(18) ELOAD(19)

  // ---- init nets (distributed): exact f32 b (state 0) ----
  const int jlo = rB ? (20 + p) : p;
  float nlo = bvec[jlo];
  float nhi = (p < 4) ? bvec[jlo + 16] : -FLT_MAX;
  const double bj = (double)bvec[jc];

  float s32a = 0.0f, s32b = 0.0f;   // bit-exact f32 state walk (d=lane, lane+64)
  float* outb = out + (size_t)batch * Ln * Vn;
  const double2* st2 = (const double2*)st64;
  const float*   Wsc = Ws + jc;

  for (int tb = 0; tb < Ln / TB; ++tb) {
    // per-lane token reg: lane u (0..31) holds token for step u of this block
    int tok = (int)aidx[tb * TB + pos];

    unsigned long long q0 = 0ull, q1 = 0ull, q2 = 0ull;  // 32 x 5-bit oidx

#pragma unroll 1
    for (int u = 0; u < TB; ++u) {    // rolled: ONE switch instance
      const int as = __builtin_amdgcn_readlane(tok, u);   // off-chain, SGPR

      // ---- argmax: 3-level max3/ror reduce; ballot index extraction ----
      float m = fmaxf(nlo, nhi);
      m = rowmax16(m);
      const unsigned long long bLo = __ballot(nlo == m);
      const unsigned long long bHi = __ballot(nhi == m);
      const unsigned wLoc = ((unsigned)bLo & 0xFFFFu) | (((unsigned)bHi & 0xFu) << 16);
      const unsigned wScl = ((unsigned)(bLo >> 16) & 0xFFFFu) |
                            (((unsigned)(bHi >> 16) & 0xFu) << 16);
      const int locI = (int)__builtin_ctz(wLoc);   // first-max = smallest j
      const int sclI = (int)__builtin_ctz(wScl);

      // oidx = (inv20(scale) * (a + 20 - loc)) mod 20  (pure SALU, uniform)
      const int r = as + Vn - locI;                // in [1, 39]
      const int inv = (sclI & 1) ? (int)((INVT >> ((sclI >> 1) * 5)) & 31ull) : 0;
      const int oidx = mod20(inv * r);             // inv*r <= 741, magic exact

      // ---- net update: wave-uniform switch -> scalar branch tree + 2 v_add.
      //      Unconditional (incl. u==TB-1): exact reference semantics. ----
      switch (oidx) {
        case 0:  nlo += eL0;  nhi += eH0;  break;
        case 1:  nlo += eL1;  nhi += eH1;  break;
        case 2:  nlo += eL2;  nhi += eH2;  break;
        case 3:  nlo += eL3;  nhi += eH3;  break;
        case 4:  nlo += eL4;  nhi += eH4;  break;
        case 5:  nlo += eL5;  nhi += eH5;  break;
        case 6:  nlo += eL6;  nhi += eH6;  break;
        case 7:  nlo += eL7;  nhi += eH7;  break;
        case 8:  nlo += eL8;  nhi += eH8;  break;
        case 9:  nlo += eL9;  nhi += eH9;  break;
        case 10: nlo += eL10; nhi += eH10; break;
        case 11: nlo += eL11; nhi += eH11; break;
        case 12: nlo += eL12; nhi += eH12; break;
        case 13: nlo += eL13; nhi += eH13; break;
        case 14: nlo += eL14; nhi += eH14; break;
        case 15: nlo += eL15; nhi += eH15; break;
        case 16: nlo += eL16; nhi += eH16; break;
        case 17: nlo += eL17; nhi += eH17; break;
        case 18: nlo += eL18; nhi += eH18; break;
        case 19: nlo += eL19; nhi += eH19; break;
        default: __builtin_unreachable();
      }

      // pack oidx into SGPR u64s (runtime shift, all SALU, off-chain)
      const int sh = (u < 12) ? 5 * u : (u < 24) ? 5 * (u - 12) : 5 * (u - 24);
      const unsigned long long w = (unsigned long long)(unsigned)oidx << sh;
      if (u < 12)      q0 |= w;
      else if (u < 24) q1 |= w;
      else             q2 |= w;
    }

    // ---- batched one-hot writeback: 640 floats, coalesced (10/lane) ----
    {
      const int rl   = lane >> 1;               // step 0..31 of the block
      const int half = lane & 1;                // cols 0-9 or 10-19
      const unsigned long long w = (rl < 12) ? q0 : (rl < 24) ? q1 : q2;
      const int sh = 5 * ((rl < 12) ? rl : (rl < 24) ? (rl - 12) : (rl - 24));
      const int od = (int)((w >> sh) & 31ull);
      float* ob = outb + (size_t)tb * (TB * Vn) + rl * Vn + half * 10;
      const int c0 = half * 10;
#pragma unroll
      for (int c = 0; c < 10; ++c)
        ob[c] = (c0 + c == od) ? 1.0f : 0.0f;
    }

    if (tb != Ln / TB - 1) {
      // ---- deferred exact f32 state walk: same order/values as per-step ----
#pragma unroll
      for (int u = 0; u < TB; ++u) {
        const unsigned long long w = (u < 12) ? q0 : (u < 24) ? q1 : q2;
        const int sh = 5 * ((u < 12) ? u : (u < 24) ? (u - 12) : (u - 24));
        const int ou = (int)((w >> sh) & 31ull);
        s32a += embd[ou * Dn + lane];
        s32b += embd[ou * Dn + lane + 64];
      }
      // ---- Resync every OTHER block (window 64): proven R9 numerics ----
      if (tb & 1) {
        st64[lane]      = (double)s32a;
        st64[lane + 64] = (double)s32b;
        double a0 = 0.0, a1 = 0.0, a2 = 0.0, a3 = 0.0;
#pragma unroll
        for (int d = 0; d < Dn; d += 4) {
          const double2 sA = st2[d >> 1];
          const double2 sB = st2[(d >> 1) + 1];
          a0 = __builtin_fma(sA.x, (double)Wsc[(d + 0) * NJ], a0);
          a1 = __builtin_fma(sA.y, (double)Wsc[(d + 1) * NJ], a1);
          a2 = __builtin_fma(sB.x, (double)Wsc[(d + 2) * NJ], a2);
          a3 = __builtin_fma(sB.y, (double)Wsc[(d + 3) * NJ], a3);
        }
        if (own) nets40[jm] = (float)(((a0 + a1) + (a2 + a3)) + bj);
        nlo = nets40[rB * 20 + p];
        nhi = (p < 4) ? nets40[rB * 20 + 16 + p] : -FLT_MAX;
      }
    }
  }
}

extern "C" void kernel_launch(void* const* d_in, const int* in_sizes, int n_in,
                              void* d_out, int out_size, void* d_ws, size_t ws_size,
                              hipStream_t stream) {
  const float* x   = (const float*)d_in[0];
  const float* emb = (const float*)d_in[1];
  const float* W   = (const float*)d_in[2];
  const float* b   = (const float*)d_in[3];
  float* out = (float*)d_out;
  hipLaunchKernelGGL(daf_chain, dim3(Bn), dim3(64), 0, stream,
                     x, emb, W, b, out);
}

// Round 17
// 225.091 us; speedup vs baseline: 1.8381x; 1.8381x over previous
//
#include <hip/hip_runtime.h>
#include <cfloat>

// Problem constants (match reference)
constexpr int Bn = 1024, Ln = 1024, Vn = 20, Dn = 128;
constexpr int NJ = 2 * Vn;      // 40 output columns
constexpr int TB = 32;          // steps per block (writeback granularity only)

// v mod 20 for 0 <= v <= ~4000 (magic multiply, exact in this range)
__device__ __forceinline__ int mod20(int v) { return v - 20 * ((v * 205) >> 12); }

// ---- DPP helpers (16-lane row reduce, pure VALU) ----
template<int CTRL>
__device__ __forceinline__ float dpp_mov(float v) {
  return __int_as_float(
      __builtin_amdgcn_update_dpp(0, __float_as_int(v), CTRL, 0xF, 0xF, false));
}
template<int CTRL>
__device__ __forceinline__ float dpp_max(float v) {
  return fmaxf(v, dpp_mov<CTRL>(v));
}
__device__ __forceinline__ float max3f(float a, float b, float c) {
  return fmaxf(fmaxf(a, b), c);   // fuses to v_max3_f32
}
// 3-level reduce (proven R13): pair max, then max3 over rotations.
__device__ __forceinline__ float rowmax16(float v) {
  const float a1 = dpp_max<0xB1>(v);                               // pair max
  const float t2 = max3f(a1, dpp_mov<0x122>(a1), dpp_mov<0x124>(a1));
  return max3f(t2, dpp_mov<0x126>(t2), dpp_mov<0x12C>(t2));
}

// inv mod 20 packed table: 5-bit entries for odd s, indexed by s>>1
constexpr unsigned long long INVT =
    (1ull << 0) | (7ull << 5) | (0ull << 10) | (3ull << 15) | (9ull << 20) |
    (11ull << 25) | (17ull << 30) | (0ull << 35) | (13ull << 40) | (19ull << 45);

__global__ __launch_bounds__(64, 1) void daf_chain(
    const float* __restrict__ x, const float* __restrict__ emb,
    const float* __restrict__ W, const float* __restrict__ bvec,
    float* __restrict__ out)
{
  __shared__ float Ws[Dn * NJ];                   // 20480 B: W row-major f32
  __shared__ alignas(16) double ewd64[Vn * 64];   // 10240 B: EW f64 {lo,hi}/pos
  __shared__ alignas(16) unsigned char aidx[Ln];  //  1024 B: token index per step
  // total 31744 B -> >=4 blocks/CU

  const int lane = threadIdx.x;
  const int batch = blockIdx.x;
  const int p   = lane & 15;          // position within row
  const int rB  = (lane >> 4) & 1;    // 0 = loc row, 1 = scale row
  const int pos = lane & 31;          // row-pair position (lanes 32..63 mirror)

  // ---- Prologue: stage W; extract token indices (coalesced float4) ----
  // Single-wave block: LDS ops complete in-order within the wave -> no barriers.
  for (int i = lane; i < Dn * NJ; i += 64) Ws[i] = W[i];
  const float4* xb4 = (const float4*)(x + (size_t)batch * Ln * Vn);
  for (int i = lane; i < Ln * (Vn / 4); i += 64) {
    const float4 v = xb4[i];
    const int row = i / 5, cb = (i % 5) * 4;
    if (v.x > 0.5f) aidx[row] = (unsigned char)(cb + 0);
    if (v.y > 0.5f) aidx[row] = (unsigned char)(cb + 1);
    if (v.z > 0.5f) aidx[row] = (unsigned char)(cb + 2);
    if (v.w > 0.5f) aidx[row] = (unsigned char)(cb + 3);
  }

  // ---- EW64[k][j] = f64 dot(emb[k], W[:,j]), stored f64 distributed (R7
  //      layout). emb read from global (L1/L2-hot, prologue-only). ----
  for (int e = lane; e < Vn * NJ; e += 64) {
    const int k = e / NJ, j = e - k * NJ;
    double acc = 0.0;
#pragma unroll 4
    for (int d = 0; d < Dn; ++d)
      acc = __builtin_fma((double)emb[k * Dn + d], (double)Ws[d * NJ + j], acc);
    int q, slot;
    if (j < 16)      { q = j;             slot = 0; }
    else if (j < 20) { q = j - 16;        slot = 1; }
    else if (j < 36) { q = 16 + (j - 20); slot = 0; }
    else             { q = 16 + (j - 36); slot = 1; }
    ewd64[k * 64 + q * 2 + slot] = acc;
  }
  if ((pos & 15) >= 4)   // zero undefined hi slots so (-DBL_MAX += 0) stays put
    for (int k = 0; k < Vn; ++k) ewd64[k * 64 + pos * 2 + 1] = 0.0;

  // ---- init nets (distributed, f64): exact b (state 0) ----
  const int jlo = rB ? (20 + p) : p;
  double nlo64 = (double)bvec[jlo];
  double nhi64 = (p < 4) ? (double)bvec[jlo + 16] : -DBL_MAX;

  float* outb = out + (size_t)batch * Ln * Vn;

  for (int tb = 0; tb < Ln / TB; ++tb) {
    // token prefetch: 32 tokens -> 8 SGPRs (two broadcast b128 reads)
    const uint4 tva = *(const uint4*)(aidx + tb * TB);
    const uint4 tvb = *(const uint4*)(aidx + tb * TB + 16);
    const int tk0 = __builtin_amdgcn_readfirstlane((int)tva.x);
    const int tk1 = __builtin_amdgcn_readfirstlane((int)tva.y);
    const int tk2 = __builtin_amdgcn_readfirstlane((int)tva.z);
    const int tk3 = __builtin_amdgcn_readfirstlane((int)tva.w);
    const int tk4 = __builtin_amdgcn_readfirstlane((int)tvb.x);
    const int tk5 = __builtin_amdgcn_readfirstlane((int)tvb.y);
    const int tk6 = __builtin_amdgcn_readfirstlane((int)tvb.z);
    const int tk7 = __builtin_amdgcn_readfirstlane((int)tvb.w);

    unsigned long long q0 = 0ull, q1 = 0ull, q2 = 0ull;  // 32 x 5-bit oidx

#pragma unroll
    for (int u = 0; u < TB; ++u) {
      const int tw = (u < 4) ? tk0 : (u < 8) ? tk1 : (u < 12) ? tk2 :
                     (u < 16) ? tk3 : (u < 20) ? tk4 : (u < 24) ? tk5 :
                     (u < 28) ? tk6 : tk7;
      const int as = (tw >> ((u & 3) * 8)) & 0xFF;   // SALU extract

      // ---- argmax keys: f32 casts of the exact f64 nets ----
      const float klo = (float)nlo64;
      const float khi = (float)nhi64;   // -DBL_MAX -> -inf for idle hi slots
      float m = fmaxf(klo, khi);
      m = rowmax16(m);
      const unsigned long long bLo = __ballot(klo == m);
      const unsigned long long bHi = __ballot(khi == m);
      const unsigned wLoc = ((unsigned)bLo & 0xFFFFu) | (((unsigned)bHi & 0xFu) << 16);
      const unsigned wScl = ((unsigned)(bLo >> 16) & 0xFFFFu) |
                            (((unsigned)(bHi >> 16) & 0xFu) << 16);
      const int locI = (int)__builtin_ctz(wLoc);   // first-max = smallest j
      const int sclI = (int)__builtin_ctz(wScl);

      // oidx = (inv20(scale) * (a + 20 - loc)) mod 20  (pure SALU, uniform)
      const int r = as + Vn - locI;                // in [1, 39]
      const int inv = (sclI & 1) ? (int)((INVT >> ((sclI >> 1) * 5)) & 31ull) : 0;
      const int oidx = mod20(inv * r);             // inv*r <= 741, magic exact

      // ---- net update: one ds_read_b128, f64 adds. Unconditional:
      //      exact reference semantics; zero drift (f64-exact sums). ----
      {
        const double2 e = *(const double2*)(ewd64 + oidx * 64 + pos * 2);
        nlo64 += e.x; nhi64 += e.y;
      }

      // pack oidx (SALU, off-chain): 12 / 12 / 8 per u64
      if (u < 12)      q0 |= (unsigned long long)(unsigned)oidx << (5 * u);
      else if (u < 24) q1 |= (unsigned long long)(unsigned)oidx << (5 * (u - 12));
      else             q2 |= (unsigned long long)(unsigned)oidx << (5 * (u - 24));
    }

    // ---- batched one-hot writeback: 640 floats, coalesced (10/lane) ----
    {
      const int rl   = lane >> 1;               // step 0..31 of the block
      const int half = lane & 1;                // cols 0-9 or 10-19
      const unsigned long long w = (rl < 12) ? q0 : (rl < 24) ? q1 : q2;
      const int sh = 5 * ((rl < 12) ? rl : (rl < 24) ? (rl - 12) : (rl - 24));
      const int od = (int)((w >> sh) & 31ull);
      float* ob = outb + (size_t)tb * (TB * Vn) + rl * Vn + half * 10;
      const int c0 = half * 10;
#pragma unroll
      for (int c = 0; c < 10; ++c)
        ob[c] = (c0 + c == od) ? 1.0f : 0.0f;
    }
  }
}

extern "C" void kernel_launch(void* const* d_in, const int* in_sizes, int n_in,
                              void* d_out, int out_size, void* d_ws, size_t ws_size,
                              hipStream_t stream) {
  const float* x   = (const float*)d_in[0];
  const float* emb = (const float*)d_in[1];
  const float* W   = (const float*)d_in[2];
  const float* b   = (const float*)d_in[3];
  float* out = (float*)d_out;
  hipLaunchKernelGGL(daf_chain, dim3(Bn), dim3(64), 0, stream,
                     x, emb, W, b, out);
}